// Round 1
// baseline (179.861 us; speedup 1.0000x reference)
//
#include <hip/hip_runtime.h>

// HighOrderActivationA: per (b,g): sort 4 inputs asc with argsort indices,
// coef = [s0, s1-s0, s2-s1, s3-s2], idx[k] = suffix-sum of (1<<ind[j]) for j>=k,
// out[b,g,:] = sum_k coef[k] * params[g, idx[k], :]   (O=16)
//
// B=8192, G=256, arity=4, O=16, fp32.  Memory-bound: 32MB read + 128MB write.

#define TB 16          // b-rows per block
#define TG 16          // groups per block
#define TSTRIDE 260    // 16 rows * 16 floats + 4 pad floats (bank-spread)

__global__ __launch_bounds__(256) void hoa_kernel(
    const float* __restrict__ X, const float* __restrict__ P,
    float* __restrict__ out, int B, int G)
{
    __shared__ float lds[TG * TSTRIDE];   // 16.25 KB

    const int tid = threadIdx.x;
    const int g0 = blockIdx.y * TG;
    const int b0 = blockIdx.x * TB;

    // ---- stage TG param tables (TG * 256 floats) into LDS, float4-coalesced ----
    #pragma unroll
    for (int i = 0; i < (TG * 64) / 256; ++i) {   // 1024 float4 chunks / 256 threads = 4
        int ci = tid + i * 256;                   // chunk id 0..1023
        int table = ci >> 6;                      // 64 float4 chunks per table
        int within = ci & 63;
        float4 v = *reinterpret_cast<const float4*>(
            P + (size_t)(g0 + table) * 256 + within * 4);
        *reinterpret_cast<float4*>(&lds[table * TSTRIDE + within * 4]) = v;
    }
    __syncthreads();

    const int gg = tid & (TG - 1);
    const int bb = tid >> 4;
    const int b  = b0 + bb;
    const int g  = g0 + gg;
    if (b >= B) return;

    // ---- load 4 inputs for this (b,g): contiguous float4 ----
    float4 x = *reinterpret_cast<const float4*>(X + (size_t)b * (G * 4) + g * 4);
    float v0 = x.x, v1 = x.y, v2 = x.z, v3 = x.w;
    int i0 = 0, i1 = 1, i2 = 2, i3 = 3;

    // ---- branchless 4-element sorting network with index tracking ----
#define CSWAP(va, vb, ia, ib)                         \
    {                                                 \
        bool sw_ = (va) > (vb);                       \
        float lo_ = sw_ ? (vb) : (va);                \
        float hi_ = sw_ ? (va) : (vb);                \
        int il_ = sw_ ? (ib) : (ia);                  \
        int ih_ = sw_ ? (ia) : (ib);                  \
        (va) = lo_; (vb) = hi_; (ia) = il_; (ib) = ih_; \
    }
    CSWAP(v0, v1, i0, i1);
    CSWAP(v2, v3, i2, i3);
    CSWAP(v0, v2, i0, i2);
    CSWAP(v1, v3, i1, i3);
    CSWAP(v1, v2, i1, i2);
#undef CSWAP

    // ---- coefficients & suffix-sum bit indices ----
    float c0 = v0, c1 = v1 - v0, c2 = v2 - v1, c3 = v3 - v2;
    int p0 = 1 << i0, p1 = 1 << i1, p3 = 1 << i3;
    int idx0 = 15;                 // all bits set
    int idx1 = 15 ^ p0;            // drop smallest's bit
    int idx2 = idx1 ^ p1;
    int idx3 = p3;

    // ---- gather 4 rows (16 floats each) from this group's LDS table ----
    const float* tab = &lds[gg * TSTRIDE];
    const float4* r0 = reinterpret_cast<const float4*>(tab + idx0 * 16);
    const float4* r1 = reinterpret_cast<const float4*>(tab + idx1 * 16);
    const float4* r2 = reinterpret_cast<const float4*>(tab + idx2 * 16);
    const float4* r3 = reinterpret_cast<const float4*>(tab + idx3 * 16);

    float* ob = out + (size_t)b * (G * 16) + g * 16;
    #pragma unroll
    for (int c = 0; c < 4; ++c) {
        float4 A = r0[c], Bv = r1[c], C = r2[c], D = r3[c];
        float4 o;
        o.x = fmaf(c3, D.x, fmaf(c2, C.x, fmaf(c1, Bv.x, c0 * A.x)));
        o.y = fmaf(c3, D.y, fmaf(c2, C.y, fmaf(c1, Bv.y, c0 * A.y)));
        o.z = fmaf(c3, D.z, fmaf(c2, C.z, fmaf(c1, Bv.z, c0 * A.z)));
        o.w = fmaf(c3, D.w, fmaf(c2, C.w, fmaf(c1, Bv.w, c0 * A.w)));
        reinterpret_cast<float4*>(ob)[c] = o;
    }
}

extern "C" void kernel_launch(void* const* d_in, const int* in_sizes, int n_in,
                              void* d_out, int out_size, void* d_ws, size_t ws_size,
                              hipStream_t stream) {
    const float* X = (const float*)d_in[0];
    const float* P = (const float*)d_in[1];
    float* out = (float*)d_out;

    // params: [G, 16, 16] -> G = size/256 ; X: [B, G*4] -> B = size/(G*4)
    int G = in_sizes[1] / 256;
    int B = in_sizes[0] / (G * 4);

    dim3 grid((B + TB - 1) / TB, G / TG);
    hipLaunchKernelGGL(hoa_kernel, grid, dim3(256), 0, stream, X, P, out, B, G);
}

// Round 2
// 176.229 us; speedup vs baseline: 1.0206x; 1.0206x over previous
//
#include <hip/hip_runtime.h>

// HighOrderActivationA: per (b,g): sort 4 inputs asc with argsort indices,
// coef = [s0, s1-s0, s2-s1, s3-s2], idx[k] = suffix-sum of (1<<ind[j]) for j>=k,
// out[b,g,:] = sum_k coef[k] * params[g, idx[k], :]   (O=16)
//
// B=8192, G=256, arity=4, O=16, fp32.  Memory-bound: 32MB read + 128MB write.
//
// Thread mapping: one thread per (b, g, c) where c is a float4 chunk of the
// 16 outputs.  Sort is recomputed by the 4 sibling threads (VALU is ~idle);
// in exchange every global store instruction is a fully contiguous 1 KB
// wave-write (the R0 kernel wrote 16B-every-64B, 4x the write transactions).

#define TB 16          // b-rows per block
#define TG 16          // groups per block
#define TSTRIDE 260    // 16 rows * 16 floats + 4 pad (65 float4, odd -> bank spread)

__global__ __launch_bounds__(1024) void hoa_kernel(
    const float* __restrict__ X, const float* __restrict__ P,
    float* __restrict__ out, int B, int G)
{
    __shared__ float lds[TG * TSTRIDE];   // 16.25 KB

    const int tid = threadIdx.x;
    const int g0 = blockIdx.y * TG;
    const int b0 = blockIdx.x * TB;

    // ---- stage TG param tables (16 tables x 64 float4 = 1024 float4) ----
    {
        int table = tid >> 6;                 // 0..15
        int within = tid & 63;                // float4 index within table
        float4 v = *reinterpret_cast<const float4*>(
            P + (size_t)(g0 + table) * 256 + within * 4);
        *reinterpret_cast<float4*>(&lds[table * TSTRIDE + within * 4]) = v;
    }
    __syncthreads();

    const int c  = tid & 3;          // output float4 chunk
    const int gg = (tid >> 2) & 15;  // group within tile
    const int bb = tid >> 6;         // b-row within tile (== wave id)
    const int b  = b0 + bb;
    const int g  = g0 + gg;
    if (b >= B) return;

    // ---- load 4 inputs for this (b,g): 4 sibling lanes share the address ----
    float4 x = *reinterpret_cast<const float4*>(X + (size_t)b * (G * 4) + g * 4);
    float v0 = x.x, v1 = x.y, v2 = x.z, v3 = x.w;
    int i0 = 0, i1 = 1, i2 = 2, i3 = 3;

    // ---- branchless 4-element sorting network with index tracking ----
#define CSWAP(va, vb, ia, ib)                         \
    {                                                 \
        bool sw_ = (va) > (vb);                       \
        float lo_ = sw_ ? (vb) : (va);                \
        float hi_ = sw_ ? (va) : (vb);                \
        int il_ = sw_ ? (ib) : (ia);                  \
        int ih_ = sw_ ? (ia) : (ib);                  \
        (va) = lo_; (vb) = hi_; (ia) = il_; (ib) = ih_; \
    }
    CSWAP(v0, v1, i0, i1);
    CSWAP(v2, v3, i2, i3);
    CSWAP(v0, v2, i0, i2);
    CSWAP(v1, v3, i1, i3);
    CSWAP(v1, v2, i1, i2);
#undef CSWAP

    // ---- coefficients & suffix-sum bit indices ----
    float c0 = v0, c1 = v1 - v0, c2 = v2 - v1, c3 = v3 - v2;
    int idx0 = 15;
    int idx1 = 15 ^ (1 << i0);
    int idx2 = idx1 ^ (1 << i1);
    int idx3 = 1 << i3;

    // ---- gather this chunk (float4) of 4 table rows from LDS ----
    const float* tab = &lds[gg * TSTRIDE + c * 4];
    float4 A  = *reinterpret_cast<const float4*>(tab + idx0 * 16);
    float4 Bv = *reinterpret_cast<const float4*>(tab + idx1 * 16);
    float4 C  = *reinterpret_cast<const float4*>(tab + idx2 * 16);
    float4 D  = *reinterpret_cast<const float4*>(tab + idx3 * 16);

    float4 o;
    o.x = fmaf(c3, D.x, fmaf(c2, C.x, fmaf(c1, Bv.x, c0 * A.x)));
    o.y = fmaf(c3, D.y, fmaf(c2, C.y, fmaf(c1, Bv.y, c0 * A.y)));
    o.z = fmaf(c3, D.z, fmaf(c2, C.z, fmaf(c1, Bv.z, c0 * A.z)));
    o.w = fmaf(c3, D.w, fmaf(c2, C.w, fmaf(c1, Bv.w, c0 * A.w)));

    // ---- fully coalesced store: lanes (c,gg) are consecutive float4s ----
    *reinterpret_cast<float4*>(out + (size_t)b * (G * 16) + g * 16 + c * 4) = o;
}

extern "C" void kernel_launch(void* const* d_in, const int* in_sizes, int n_in,
                              void* d_out, int out_size, void* d_ws, size_t ws_size,
                              hipStream_t stream) {
    const float* X = (const float*)d_in[0];
    const float* P = (const float*)d_in[1];
    float* out = (float*)d_out;

    // params: [G, 16, 16] -> G = size/256 ; X: [B, G*4] -> B = size/(G*4)
    int G = in_sizes[1] / 256;
    int B = in_sizes[0] / (G * 4);

    dim3 grid((B + TB - 1) / TB, G / TG);
    hipLaunchKernelGGL(hoa_kernel, grid, dim3(1024), 0, stream, X, P, out, B, G);
}